// Round 1
// 401.263 us; speedup vs baseline: 1.0020x; 1.0020x over previous
//
#include <hip/hip_runtime.h>

// Problem constants (from reference)
#define BB 4
#define CC 256
#define HH 256
#define WW 256
#define N_BOX 64
#define SS 7
#define NPTS (SS * SS)        // 49
#define NROI (BB * N_BOX)     // 256
#define CG 32                 // channels per block (was 64): 2048 blocks -> 8 blocks/CU -> 32 waves/CU
#define NG (CC / CG)          // 8 channel groups
#define ITEMS (CG * NPTS)     // 1568 output elements per block
#define MAIN_ITERS (ITEMS / 256)        // 6 uniform iterations
#define TAIL (ITEMS - MAIN_ITERS * 256) // 32 leftover elements
#define ROI_SCALE 0.25f

__global__ __launch_bounds__(256, 8) void rotated_roi_align_kernel(
    const float* __restrict__ feats,   // (B, C, H, W)
    const float* __restrict__ rois,    // (B, N_BOX, 5): cx, cy, w, h, theta (world coords)
    float* __restrict__ out)           // (B*N_BOX, C, S, S)
{
    // Packed per-point sampling state: one b128 read each for offsets and weights.
    __shared__ int4   s_off[NPTS];     // clamped flat offsets y*W+x, corners 0..3 in xyzw
    __shared__ float4 s_w[NPTS];       // bilinear weight * validity, corners 0..3 in xyzw

    const int r   = blockIdx.x;        // roi index 0..255
    const int cq  = blockIdx.y;        // channel group 0..NG-1
    const int b   = r >> 6;            // r / N_BOX
    const int tid = threadIdx.x;

    // ---- Per-point precompute (threads 0..48) ----
    if (tid < NPTS) {
        const float cx = rois[r * 5 + 0] * ROI_SCALE;
        const float cy = rois[r * 5 + 1] * ROI_SCALE;
        const float bw = rois[r * 5 + 2] * ROI_SCALE;
        const float bh = rois[r * 5 + 3] * ROI_SCALE;
        const float th = rois[r * 5 + 4];
        const float ct = cosf(th);
        const float st = sinf(th);

        const int py = tid / SS;
        const int px = tid - py * SS;
        // lin = (k + 0.5)/S - 0.5
        const float lu = (px + 0.5f) / (float)SS - 0.5f;
        const float lv = (py + 0.5f) / (float)SS - 0.5f;
        const float u = lu * bw;
        const float v = lv * bh;
        const float x = cx + u * ct - v * st;
        const float y = cy + u * st + v * ct;

        const float x0f = floorf(x), y0f = floorf(y);
        const float x1f = x0f + 1.0f, y1f = y0f + 1.0f;
        const float wx1 = x - x0f, wx0 = 1.0f - wx1;
        const float wy1 = y - y0f, wy0 = 1.0f - wy1;

        const bool vx0 = (x0f >= 0.0f) && (x0f <= (float)(WW - 1));
        const bool vx1 = (x1f >= 0.0f) && (x1f <= (float)(WW - 1));
        const bool vy0 = (y0f >= 0.0f) && (y0f <= (float)(HH - 1));
        const bool vy1 = (y1f >= 0.0f) && (y1f <= (float)(HH - 1));

        const int x0c = min(max((int)x0f, 0), WW - 1);
        const int x1c = min(max((int)x1f, 0), WW - 1);
        const int y0c = min(max((int)y0f, 0), HH - 1);
        const int y1c = min(max((int)y1f, 0), HH - 1);

        s_off[tid] = make_int4(y0c * WW + x0c,
                               y0c * WW + x1c,
                               y1c * WW + x0c,
                               y1c * WW + x1c);
        s_w[tid] = make_float4((vx0 && vy0) ? wx0 * wy0 : 0.0f,
                               (vx1 && vy0) ? wx1 * wy0 : 0.0f,
                               (vx0 && vy1) ? wx0 * wy1 : 0.0f,
                               (vx1 && vy1) ? wx1 * wy1 : 0.0f);
    }
    __syncthreads();

    // ---- Gather + coalesced write ----
    // Output for this block is the contiguous range
    //   out[r*C*49 + cq*CG*49 .. +ITEMS), laid out as (c_local, p) row-major —
    // identical to flat index i, so stores are fully coalesced.
    const float* plane_base = feats + ((size_t)b * CC + (size_t)cq * CG) * (size_t)(HH * WW);
    float* ob = out + (size_t)r * (CC * NPTS) + (size_t)cq * (CG * NPTS);

    // i = tid + 256*k ; track (cl, p) incrementally: 256 = 5*49 + 11
    int cl = tid / NPTS;              // one magic-mul, once
    int p  = tid - cl * NPTS;

    #pragma unroll 2
    for (int k = 0; k < MAIN_ITERS; ++k) {
        const float* plane = plane_base + ((size_t)cl << 16);   // H*W = 1<<16
        const int4   o  = s_off[p];
        const float4 wv = s_w[p];
        const float v0 = plane[o.x];
        const float v1 = plane[o.y];
        const float v2 = plane[o.z];
        const float v3 = plane[o.w];
        const float res = wv.x * v0 + wv.y * v1 + wv.z * v2 + wv.w * v3;
        // write-once output: non-temporal so it doesn't evict feats lines from L2
        __builtin_nontemporal_store(res, ob + tid + (k << 8));
        p += 11; cl += 5;
        if (p >= NPTS) { p -= NPTS; ++cl; }
    }

    // tail: last TAIL elements (i = MAIN_ITERS*256 + tid)
    if (tid < TAIL) {
        const int i  = MAIN_ITERS * 256 + tid;
        const int c2 = i / NPTS;
        const int p2 = i - c2 * NPTS;
        const float* plane = plane_base + ((size_t)c2 << 16);
        const int4   o  = s_off[p2];
        const float4 wv = s_w[p2];
        const float v0 = plane[o.x];
        const float v1 = plane[o.y];
        const float v2 = plane[o.z];
        const float v3 = plane[o.w];
        const float res = wv.x * v0 + wv.y * v1 + wv.z * v2 + wv.w * v3;
        __builtin_nontemporal_store(res, ob + i);
    }
}

extern "C" void kernel_launch(void* const* d_in, const int* in_sizes, int n_in,
                              void* d_out, int out_size, void* d_ws, size_t ws_size,
                              hipStream_t stream) {
    const float* feats = (const float*)d_in[0];
    const float* rois  = (const float*)d_in[1];
    float* out = (float*)d_out;

    dim3 grid(NROI, NG);   // 256 rois x 8 channel groups = 2048 blocks
    rotated_roi_align_kernel<<<grid, 256, 0, stream>>>(feats, rois, out);
}

// Round 2
// 383.971 us; speedup vs baseline: 1.0471x; 1.0450x over previous
//
#include <hip/hip_runtime.h>

// Problem constants (from reference)
#define BB 4
#define CC 256
#define HH 256
#define WW 256
#define N_BOX 64
#define SS 7
#define NPTS (SS * SS)        // 49
#define NROI (BB * N_BOX)     // 256
#define CG 32                 // channels per block: 2048 blocks -> 8 blocks/CU -> 32 waves/CU
#define NG (CC / CG)          // 8 channel groups
#define ITEMS (CG * NPTS)     // 1568 output elements per block
#define MAIN_ITERS (ITEMS / 256)        // 6 uniform iterations
#define TAIL (ITEMS - MAIN_ITERS * 256) // 32 leftover elements
#define ROI_SCALE 0.25f

// 8B vector with 4B alignment guarantee: x0/x1 pair base can be odd.
// gfx950 supports unaligned global access; worst case backend splits into
// two dword loads (= status quo ante).
typedef float f2 __attribute__((ext_vector_type(2), aligned(4)));

__global__ __launch_bounds__(256, 8) void rotated_roi_align_kernel(
    const float* __restrict__ feats,   // (B, C, H, W)
    const float* __restrict__ rois,    // (B, N_BOX, 5): cx, cy, w, h, theta (world coords)
    float* __restrict__ out)           // (B*N_BOX, C, S, S)
{
    // Per-point sampling state, pair-merged along x:
    //   s_o[p] = (y0c*W+xb, y1c*W+xb)   -- base offsets of the two row-pairs
    //   s_q[p] = (wA, wB, wy0v, wy1v)   -- x-weights for (xb, xb+1), y-row weights
    __shared__ int2   s_o[NPTS];
    __shared__ float4 s_q[NPTS];

    const int r   = blockIdx.x;        // roi index 0..255
    const int cq  = blockIdx.y;        // channel group 0..NG-1
    const int b   = r >> 6;            // r / N_BOX
    const int tid = threadIdx.x;

    // ---- Per-point precompute (threads 0..48) ----
    if (tid < NPTS) {
        const float cx = rois[r * 5 + 0] * ROI_SCALE;
        const float cy = rois[r * 5 + 1] * ROI_SCALE;
        const float bw = rois[r * 5 + 2] * ROI_SCALE;
        const float bh = rois[r * 5 + 3] * ROI_SCALE;
        const float th = rois[r * 5 + 4];
        const float ct = cosf(th);
        const float st = sinf(th);

        const int py = tid / SS;
        const int px = tid - py * SS;
        const float lu = (px + 0.5f) / (float)SS - 0.5f;
        const float lv = (py + 0.5f) / (float)SS - 0.5f;
        const float u = lu * bw;
        const float v = lv * bh;
        const float x = cx + u * ct - v * st;
        const float y = cy + u * st + v * ct;

        const float x0f = floorf(x), y0f = floorf(y);
        const float wx1 = x - x0f, wx0 = 1.0f - wx1;
        const float wy1 = y - y0f, wy0 = 1.0f - wy1;

        const int x0i = (int)x0f;          // exact: x0f is an integer-valued float
        const int x1i = x0i + 1;
        const int y0i = (int)y0f;
        const int y1i = y0i + 1;

        // per-corner validity folded into weights
        const float w0x = (x0i >= 0 && x0i <= WW - 1) ? wx0 : 0.0f;
        const float w1x = (x1i >= 0 && x1i <= WW - 1) ? wx1 : 0.0f;
        const float wy0v = (y0i >= 0 && y0i <= HH - 1) ? wy0 : 0.0f;
        const float wy1v = (y1i >= 0 && y1i <= HH - 1) ? wy1 : 0.0f;

        const int x0c = min(max(x0i, 0), WW - 1);
        const int x1c = min(max(x1i, 0), WW - 1);
        const int y0c = min(max(y0i, 0), HH - 1);
        const int y1c = min(max(y1i, 0), HH - 1);

        // pair base: both sampled columns live at (xb, xb+1)
        const int xb = min(max(x0i, 0), WW - 2);

        // redistribute the clamped x-weights onto the pair slots
        float wA = 0.0f, wB = 0.0f;
        if (x0c == xb) wA += w0x; else wB += w0x;   // x0c is xb or xb+1 by construction
        if (x1c == xb) wA += w1x; else wB += w1x;

        s_o[tid] = make_int2(y0c * WW + xb, y1c * WW + xb);
        s_q[tid] = make_float4(wA, wB, wy0v, wy1v);
    }
    __syncthreads();

    // ---- Gather + coalesced write ----
    // Output for this block: contiguous range, (c_local, p) row-major == flat i.
    const float* plane_base = feats + ((size_t)b * CC + (size_t)cq * CG) * (size_t)(HH * WW);
    float* ob = out + (size_t)r * (CC * NPTS) + (size_t)cq * (CG * NPTS);

    // i = tid + 256*k ; track (cl, p) incrementally: 256 = 5*49 + 11
    int cl = tid / NPTS;
    int p  = tid - cl * NPTS;

    #pragma unroll 3
    for (int k = 0; k < MAIN_ITERS; ++k) {
        const float* plane = plane_base + ((size_t)cl << 16);   // H*W = 1<<16
        const int2   o = s_o[p];
        const float4 q = s_q[p];
        const f2 r0 = *reinterpret_cast<const f2*>(plane + o.x);  // row y0: (xb, xb+1)
        const f2 r1 = *reinterpret_cast<const f2*>(plane + o.y);  // row y1: (xb, xb+1)
        const float res = q.z * (q.x * r0.x + q.y * r0.y)
                        + q.w * (q.x * r1.x + q.y * r1.y);
        __builtin_nontemporal_store(res, ob + tid + (k << 8));
        p += 11; cl += 5;
        if (p >= NPTS) { p -= NPTS; ++cl; }
    }

    // tail: last TAIL elements (i = MAIN_ITERS*256 + tid)
    if (tid < TAIL) {
        const int i  = MAIN_ITERS * 256 + tid;
        const int c2 = i / NPTS;
        const int p2 = i - c2 * NPTS;
        const float* plane = plane_base + ((size_t)c2 << 16);
        const int2   o = s_o[p2];
        const float4 q = s_q[p2];
        const f2 r0 = *reinterpret_cast<const f2*>(plane + o.x);
        const f2 r1 = *reinterpret_cast<const f2*>(plane + o.y);
        const float res = q.z * (q.x * r0.x + q.y * r0.y)
                        + q.w * (q.x * r1.x + q.y * r1.y);
        __builtin_nontemporal_store(res, ob + i);
    }
}

extern "C" void kernel_launch(void* const* d_in, const int* in_sizes, int n_in,
                              void* d_out, int out_size, void* d_ws, size_t ws_size,
                              hipStream_t stream) {
    const float* feats = (const float*)d_in[0];
    const float* rois  = (const float*)d_in[1];
    float* out = (float*)d_out;

    dim3 grid(NROI, NG);   // 256 rois x 8 channel groups = 2048 blocks
    rotated_roi_align_kernel<<<grid, 256, 0, stream>>>(feats, rois, out);
}

// Round 3
// 379.534 us; speedup vs baseline: 1.0594x; 1.0117x over previous
//
#include <hip/hip_runtime.h>

// Problem constants (from reference)
#define BB 4
#define CC 256
#define HH 256
#define WW 256
#define N_BOX 64
#define SS 7
#define NPTS (SS * SS)        // 49
#define NROI (BB * N_BOX)     // 256
#define CG 32                 // channels per block: 2048 blocks
#define NG (CC / CG)          // 8 channel groups
#define ITEMS (CG * NPTS)     // 1568 output elements per block
#define MAIN_ITERS (ITEMS / 256)        // 6 uniform iterations
#define TAIL (ITEMS - MAIN_ITERS * 256) // 32 leftover elements
#define ROI_SCALE 0.25f

// 8B vector with 4B alignment guarantee: x0/x1 pair base can be odd.
typedef float f2 __attribute__((ext_vector_type(2), aligned(4)));

__global__ __launch_bounds__(256, 4) void rotated_roi_align_kernel(
    const float* __restrict__ feats,   // (B, C, H, W)
    const float* __restrict__ rois,    // (B, N_BOX, 5): cx, cy, w, h, theta (world coords)
    float* __restrict__ out)           // (B*N_BOX, C, S, S)
{
    // SoA per-point state: all reads are ds_read_b32 with worst-case 2-way
    // lane aliasing (p vs p+32), which is free on CDNA4 (m136).
    __shared__ int   s_o0[NPTS];   // y0c*W + xb
    __shared__ int   s_o1[NPTS];   // y1c*W + xb
    __shared__ float s_wA[NPTS];   // x-weight at xb
    __shared__ float s_wB[NPTS];   // x-weight at xb+1
    __shared__ float s_w0[NPTS];   // y0 row weight (validity folded)
    __shared__ float s_w1[NPTS];   // y1 row weight (validity folded)

    const int r   = blockIdx.x;        // roi index 0..255
    const int cq  = blockIdx.y;        // channel group 0..NG-1
    const int b   = r >> 6;            // r / N_BOX
    const int tid = threadIdx.x;

    // ---- Per-point precompute (threads 0..48) ----
    if (tid < NPTS) {
        const float cx = rois[r * 5 + 0] * ROI_SCALE;
        const float cy = rois[r * 5 + 1] * ROI_SCALE;
        const float bw = rois[r * 5 + 2] * ROI_SCALE;
        const float bh = rois[r * 5 + 3] * ROI_SCALE;
        const float th = rois[r * 5 + 4];
        const float ct = cosf(th);
        const float st = sinf(th);

        const int py = tid / SS;
        const int px = tid - py * SS;
        const float lu = (px + 0.5f) / (float)SS - 0.5f;
        const float lv = (py + 0.5f) / (float)SS - 0.5f;
        const float u = lu * bw;
        const float v = lv * bh;
        const float x = cx + u * ct - v * st;
        const float y = cy + u * st + v * ct;

        const float x0f = floorf(x), y0f = floorf(y);
        const float wx1 = x - x0f, wx0 = 1.0f - wx1;
        const float wy1 = y - y0f, wy0 = 1.0f - wy1;

        const int x0i = (int)x0f;
        const int x1i = x0i + 1;
        const int y0i = (int)y0f;
        const int y1i = y0i + 1;

        // per-corner validity folded into weights
        const float w0x = (x0i >= 0 && x0i <= WW - 1) ? wx0 : 0.0f;
        const float w1x = (x1i >= 0 && x1i <= WW - 1) ? wx1 : 0.0f;
        const float wy0v = (y0i >= 0 && y0i <= HH - 1) ? wy0 : 0.0f;
        const float wy1v = (y1i >= 0 && y1i <= HH - 1) ? wy1 : 0.0f;

        const int x0c = min(max(x0i, 0), WW - 1);
        const int x1c = min(max(x1i, 0), WW - 1);
        const int y0c = min(max(y0i, 0), HH - 1);
        const int y1c = min(max(y1i, 0), HH - 1);

        // pair base: both sampled columns live at (xb, xb+1)
        const int xb = min(max(x0i, 0), WW - 2);

        // redistribute the clamped x-weights onto the pair slots
        float wA = 0.0f, wB = 0.0f;
        if (x0c == xb) wA += w0x; else wB += w0x;
        if (x1c == xb) wA += w1x; else wB += w1x;

        s_o0[tid] = y0c * WW + xb;
        s_o1[tid] = y1c * WW + xb;
        s_wA[tid] = wA;
        s_wB[tid] = wB;
        s_w0[tid] = wy0v;
        s_w1[tid] = wy1v;
    }
    __syncthreads();

    // ---- Gather + coalesced write ----
    const float* plane_base = feats + ((size_t)b * CC + (size_t)cq * CG) * (size_t)(HH * WW);
    float* ob = out + (size_t)r * (CC * NPTS) + (size_t)cq * (CG * NPTS) + tid;

    // Precompute the per-iteration (cl, p) walk: 256 = 5*49 + 11.
    int pk[MAIN_ITERS], clk[MAIN_ITERS];
    {
        int cl = tid / NPTS;
        int p  = tid - cl * NPTS;
        #pragma unroll
        for (int k = 0; k < MAIN_ITERS; ++k) {
            pk[k] = p; clk[k] = cl;
            p += 11; cl += 5;
            if (p >= NPTS) { p -= NPTS; ++cl; }
        }
    }

    // Phase 1: issue ALL loads (LDS state + 12 global pair-loads) so the
    // memory system sees maximum outstanding requests per wave.
    f2 r0[MAIN_ITERS], r1[MAIN_ITERS];
    float wa[MAIN_ITERS], wb[MAIN_ITERS], w0[MAIN_ITERS], w1[MAIN_ITERS];
    #pragma unroll
    for (int k = 0; k < MAIN_ITERS; ++k) {
        const int p = pk[k];
        const float* plane = plane_base + ((size_t)clk[k] << 16);  // H*W = 1<<16
        const int o0 = s_o0[p];
        const int o1 = s_o1[p];
        r0[k] = *reinterpret_cast<const f2*>(plane + o0);
        r1[k] = *reinterpret_cast<const f2*>(plane + o1);
        wa[k] = s_wA[p]; wb[k] = s_wB[p]; w0[k] = s_w0[p]; w1[k] = s_w1[p];
    }

    // Phase 2: combine + coalesced non-temporal stores.
    #pragma unroll
    for (int k = 0; k < MAIN_ITERS; ++k) {
        const float res = w0[k] * (wa[k] * r0[k].x + wb[k] * r0[k].y)
                        + w1[k] * (wa[k] * r1[k].x + wb[k] * r1[k].y);
        __builtin_nontemporal_store(res, ob + (k << 8));
    }

    // tail: last TAIL elements (i = MAIN_ITERS*256 + tid)
    if (tid < TAIL) {
        const int i  = MAIN_ITERS * 256 + tid;
        const int c2 = i / NPTS;
        const int p2 = i - c2 * NPTS;
        const float* plane = plane_base + ((size_t)c2 << 16);
        const f2 t0 = *reinterpret_cast<const f2*>(plane + s_o0[p2]);
        const f2 t1 = *reinterpret_cast<const f2*>(plane + s_o1[p2]);
        const float res = s_w0[p2] * (s_wA[p2] * t0.x + s_wB[p2] * t0.y)
                        + s_w1[p2] * (s_wA[p2] * t1.x + s_wB[p2] * t1.y);
        __builtin_nontemporal_store(res, ob + (i - tid));
    }
}

extern "C" void kernel_launch(void* const* d_in, const int* in_sizes, int n_in,
                              void* d_out, int out_size, void* d_ws, size_t ws_size,
                              hipStream_t stream) {
    const float* feats = (const float*)d_in[0];
    const float* rois  = (const float*)d_in[1];
    float* out = (float*)d_out;

    dim3 grid(NROI, NG);   // 256 rois x 8 channel groups = 2048 blocks
    rotated_roi_align_kernel<<<grid, 256, 0, stream>>>(feats, rois, out);
}